// Round 1
// baseline (154.128 us; speedup 1.0000x reference)
//
#include <hip/hip_runtime.h>
#include <math.h>

// Problem constants
#define NB 4
#define HH 64
#define WW 64
#define CC 128
#define GG 4
#define GC 32
#define PP 9
#define MPIX (NB*HH*WW)          // 16384
#define PIXC ((size_t)MPIX*CC)   // 2097152 floats

// ---------------------------------------------------------------------------
// Pack w_off (128x72) | w_mask (128x36) | zeros -> Bpack (128x128), same for bias
// ---------------------------------------------------------------------------
__global__ __launch_bounds__(256) void pack_offmask_w(
    const float* __restrict__ w_off, const float* __restrict__ b_off,
    const float* __restrict__ w_mask, const float* __restrict__ b_mask,
    float* __restrict__ Bpack, float* __restrict__ bpack)
{
    int e = blockIdx.x * 256 + threadIdx.x;
    if (e < 128 * 128) {
        int k = e >> 7, j = e & 127;
        float v = 0.f;
        if (j < 72)       v = w_off[k * 72 + j];
        else if (j < 108) v = w_mask[k * 36 + (j - 72)];
        Bpack[e] = v;
    } else if (e < 128 * 128 + 128) {
        int j = e - 128 * 128;
        float v = 0.f;
        if (j < 72)       v = b_off[j];
        else if (j < 108) v = b_mask[j - 72];
        bpack[j] = v;
    }
}

// ---------------------------------------------------------------------------
// Tiled fp32 GEMM: C[M x 128] = A[M x 128] * B[128 x 128] + bias
// grid = M/64 blocks, 256 threads. Micro-tile 4 rows x 8 cols per thread.
// ---------------------------------------------------------------------------
__global__ __launch_bounds__(256) void gemm_m128(
    const float* __restrict__ A, const float* __restrict__ B,
    const float* __restrict__ bias, float* __restrict__ C)
{
    __shared__ float sA[32][68];   // sA[k][r]: A transposed, 16B-aligned rows
    __shared__ float sB[32][128];  // sB[k][n]

    const int t  = threadIdx.x;
    const int tr = t >> 4;         // 0..15 row group
    const int tc = t & 15;         // 0..15 col group
    const int row0 = blockIdx.x << 6;

    float acc[4][8];
#pragma unroll
    for (int r = 0; r < 4; r++)
#pragma unroll
        for (int c = 0; c < 8; c++) acc[r][c] = 0.f;

    for (int kc = 0; kc < 128; kc += 32) {
        // stage A chunk (64 rows x 32 cols), transposed into sA[k][r]
#pragma unroll
        for (int i = 0; i < 2; i++) {
            int idx = t + i * 256;          // 0..511
            int r  = idx >> 3;              // 0..63
            int c4 = (idx & 7) << 2;        // 0..28
            float4 v = *(const float4*)(A + (size_t)(row0 + r) * 128 + kc + c4);
            sA[c4 + 0][r] = v.x; sA[c4 + 1][r] = v.y;
            sA[c4 + 2][r] = v.z; sA[c4 + 3][r] = v.w;
        }
        // stage B chunk (32 rows x 128 cols)
#pragma unroll
        for (int i = 0; i < 4; i++) {
            int idx = t + i * 256;          // 0..1023
            int r  = idx >> 5;              // 0..31
            int c4 = (idx & 31) << 2;       // 0..124
            *(float4*)(&sB[r][c4]) = *(const float4*)(B + (size_t)(kc + r) * 128 + c4);
        }
        __syncthreads();
#pragma unroll
        for (int k = 0; k < 32; k++) {
            float4 a  = *(const float4*)(&sA[k][tr << 2]);
            float4 b0 = *(const float4*)(&sB[k][tc << 2]);
            float4 b1 = *(const float4*)(&sB[k][64 + (tc << 2)]);
            float ar[4] = {a.x, a.y, a.z, a.w};
            float br[8] = {b0.x, b0.y, b0.z, b0.w, b1.x, b1.y, b1.z, b1.w};
#pragma unroll
            for (int r = 0; r < 4; r++)
#pragma unroll
                for (int c = 0; c < 8; c++)
                    acc[r][c] = fmaf(ar[r], br[c], acc[r][c]);
        }
        __syncthreads();
    }

    const float4 bias0 = *(const float4*)(bias + (tc << 2));
    const float4 bias1 = *(const float4*)(bias + 64 + (tc << 2));
#pragma unroll
    for (int r = 0; r < 4; r++) {
        float* crow = C + (size_t)(row0 + (tr << 2) + r) * 128;
        float4 o0 = make_float4(acc[r][0] + bias0.x, acc[r][1] + bias0.y,
                                acc[r][2] + bias0.z, acc[r][3] + bias0.w);
        float4 o1 = make_float4(acc[r][4] + bias1.x, acc[r][5] + bias1.y,
                                acc[r][6] + bias1.z, acc[r][7] + bias1.w);
        *(float4*)(crow + (tc << 2)) = o0;
        *(float4*)(crow + 64 + (tc << 2)) = o1;
    }
}

// ---------------------------------------------------------------------------
// Depthwise 3x3 conv + bias + LayerNorm(C, eps=1e-6) + exact GELU
// 8 pixels / block; 32 lanes x 4 channels per pixel.
// ---------------------------------------------------------------------------
__global__ __launch_bounds__(256) void dw_ln_gelu(
    const float* __restrict__ x, const float* __restrict__ kern,
    const float* __restrict__ kbias, const float* __restrict__ gamma,
    const float* __restrict__ beta, float* __restrict__ y)
{
    const int t  = threadIdx.x;
    const int pl = t >> 5;             // local pixel 0..7
    const int cq = (t & 31) << 2;      // channel quad 0..124
    const int pix = blockIdx.x * 8 + pl;
    const int w = pix & 63;
    const int h = (pix >> 6) & 63;
    const int b = pix >> 12;

    float4 acc = make_float4(0.f, 0.f, 0.f, 0.f);
#pragma unroll
    for (int kh = 0; kh < 3; kh++) {
        int hy = h + kh - 1;
        if (hy < 0 || hy > 63) continue;
#pragma unroll
        for (int kw = 0; kw < 3; kw++) {
            int wx = w + kw - 1;
            if (wx < 0 || wx > 63) continue;
            const float4 v  = *(const float4*)(x + (((size_t)((b * 64 + hy) * 64 + wx)) << 7) + cq);
            const float4 kv = *(const float4*)(kern + ((kh * 3 + kw) << 7) + cq);
            acc.x = fmaf(v.x, kv.x, acc.x);
            acc.y = fmaf(v.y, kv.y, acc.y);
            acc.z = fmaf(v.z, kv.z, acc.z);
            acc.w = fmaf(v.w, kv.w, acc.w);
        }
    }
    const float4 kb = *(const float4*)(kbias + cq);
    acc.x += kb.x; acc.y += kb.y; acc.z += kb.z; acc.w += kb.w;

    // LayerNorm over 128 channels: reduce across the 32 lanes of this pixel
    float s  = acc.x + acc.y + acc.z + acc.w;
    float s2 = acc.x * acc.x + acc.y * acc.y + acc.z * acc.z + acc.w * acc.w;
#pragma unroll
    for (int m = 16; m >= 1; m >>= 1) {
        s  += __shfl_xor(s, m);
        s2 += __shfl_xor(s2, m);
    }
    const float mu   = s * (1.f / 128.f);
    const float var  = s2 * (1.f / 128.f) - mu * mu;
    const float rstd = 1.f / sqrtf(var + 1e-6f);

    const float4 g  = *(const float4*)(gamma + cq);
    const float4 bb = *(const float4*)(beta + cq);
    float vv[4] = {acc.x, acc.y, acc.z, acc.w};
    float gg[4] = {g.x, g.y, g.z, g.w};
    float be[4] = {bb.x, bb.y, bb.z, bb.w};
    float4 outv;
    float* po = &outv.x;
#pragma unroll
    for (int i = 0; i < 4; i++) {
        float xh = (vv[i] - mu) * rstd * gg[i] + be[i];
        po[i] = 0.5f * xh * (1.f + erff(xh * 0.70710678118654752f));
    }
    *(float4*)(y + ((size_t)pix << 7) + cq) = outv;
}

// ---------------------------------------------------------------------------
// DCNv3 sampling core. offmask row (stride 128): [0..71]=offsets, [72..107]=mask logits.
// Thread = (pixel, group, 8-channel oct). Softmax over P=9 inline.
// ---------------------------------------------------------------------------
__global__ __launch_bounds__(256) void dcn_sample(
    const float* __restrict__ xp, const float* __restrict__ om,
    float* __restrict__ out)
{
    const int t = threadIdx.x;
    const int q = t & 3;               // channel oct within group
    const int g = (t >> 2) & 3;        // group
    const int pix = blockIdx.x * 16 + (t >> 4);
    const int w = pix & 63;
    const int h = (pix >> 6) & 63;
    const int b = pix >> 12;

    const float* ompix = om + ((size_t)pix << 7);

    // softmax over the 9 mask logits of this (pixel, group)
    float lg[9];
    float mx = -1e30f;
#pragma unroll
    for (int p = 0; p < 9; p++) {
        lg[p] = ompix[72 + g * 9 + p];
        mx = fmaxf(mx, lg[p]);
    }
    float sum = 0.f;
#pragma unroll
    for (int p = 0; p < 9; p++) { lg[p] = expf(lg[p] - mx); sum += lg[p]; }
    const float inv = 1.f / sum;

    float4 acc0 = make_float4(0.f, 0.f, 0.f, 0.f);
    float4 acc1 = make_float4(0.f, 0.f, 0.f, 0.f);
    const int chbase = g * 32 + q * 8;

#pragma unroll
    for (int p = 0; p < 9; p++) {
        const float ox = ompix[g * 18 + 2 * p];
        const float oy = ompix[g * 18 + 2 * p + 1];
        // unpadded sample coords: px = w + (p/3) - 1 + ox ; py = h + (p%3) - 1 + oy
        const float px = (float)(w + p / 3 - 1) + ox;
        const float py = (float)(h + p % 3 - 1) + oy;
        const float fx0 = floorf(px), fy0 = floorf(py);
        const int x0 = (int)fx0, y0 = (int)fy0;
        const float wx1 = px - fx0, wy1 = py - fy0;
        const float wx0 = 1.f - wx1, wy0 = 1.f - wy1;
        const float m = lg[p] * inv;
        const float cw[4] = {wy0 * wx0 * m, wy0 * wx1 * m, wy1 * wx0 * m, wy1 * wx1 * m};
        const int cx[4] = {x0, x0 + 1, x0, x0 + 1};
        const int cy[4] = {y0, y0, y0 + 1, y0 + 1};
#pragma unroll
        for (int c = 0; c < 4; c++) {
            const int xx = cx[c], yy = cy[c];
            if (xx >= 0 && xx < 64 && yy >= 0 && yy < 64) {
                const float* src = xp + (((size_t)((b * 64 + yy) * 64 + xx)) << 7) + chbase;
                const float4 v0 = *(const float4*)(src);
                const float4 v1 = *(const float4*)(src + 4);
                const float wt = cw[c];
                acc0.x = fmaf(v0.x, wt, acc0.x); acc0.y = fmaf(v0.y, wt, acc0.y);
                acc0.z = fmaf(v0.z, wt, acc0.z); acc0.w = fmaf(v0.w, wt, acc0.w);
                acc1.x = fmaf(v1.x, wt, acc1.x); acc1.y = fmaf(v1.y, wt, acc1.y);
                acc1.z = fmaf(v1.z, wt, acc1.z); acc1.w = fmaf(v1.w, wt, acc1.w);
            }
        }
    }
    float* dst = out + ((size_t)pix << 7) + chbase;
    *(float4*)(dst)     = acc0;
    *(float4*)(dst + 4) = acc1;
}

// ---------------------------------------------------------------------------
extern "C" void kernel_launch(void* const* d_in, const int* in_sizes, int n_in,
                              void* d_out, int out_size, void* d_ws, size_t ws_size,
                              hipStream_t stream)
{
    const float* input   = (const float*)d_in[0];
    const float* w_in    = (const float*)d_in[1];
    const float* b_in    = (const float*)d_in[2];
    const float* w_out   = (const float*)d_in[3];
    const float* b_out   = (const float*)d_in[4];
    const float* w_off   = (const float*)d_in[5];
    const float* b_off   = (const float*)d_in[6];
    const float* w_mask  = (const float*)d_in[7];
    const float* b_mask  = (const float*)d_in[8];
    const float* dw_kern = (const float*)d_in[9];
    const float* dw_bias = (const float*)d_in[10];
    const float* ln_g    = (const float*)d_in[11];
    const float* ln_b    = (const float*)d_in[12];
    float* out = (float*)d_out;

    float* ws      = (float*)d_ws;
    float* x_proj  = ws;                       // M*128
    float* x1      = ws + PIXC;                // M*128
    float* offmask = ws + 2 * PIXC;            // M*128 (72 off | 36 mask | 20 pad)
    float* Bpack   = ws + 3 * PIXC;            // 128*128
    float* bpack   = Bpack + 128 * 128;        // 128
    float* sampled = x1;                       // reuse: x1 dead after offmask GEMM

    pack_offmask_w<<<65, 256, 0, stream>>>(w_off, b_off, w_mask, b_mask, Bpack, bpack);
    gemm_m128<<<MPIX / 64, 256, 0, stream>>>(input, w_in, b_in, x_proj);
    dw_ln_gelu<<<MPIX / 8, 256, 0, stream>>>(input, dw_kern, dw_bias, ln_g, ln_b, x1);
    gemm_m128<<<MPIX / 64, 256, 0, stream>>>(x1, Bpack, bpack, offmask);
    dcn_sample<<<MPIX / 16, 256, 0, stream>>>(x_proj, offmask, sampled);
    gemm_m128<<<MPIX / 64, 256, 0, stream>>>(sampled, w_out, b_out, out);
}

// Round 2
// 134.546 us; speedup vs baseline: 1.1455x; 1.1455x over previous
//
#include <hip/hip_runtime.h>
#include <math.h>

// Problem constants
#define NB 4
#define HH 64
#define WW 64
#define CC 128
#define GG 4
#define GC 32
#define PP 9
#define MPIX (NB*HH*WW)          // 16384
#define PIXC ((size_t)MPIX*CC)   // 2097152 floats

typedef short bf16x8 __attribute__((ext_vector_type(8)));
typedef float f32x4  __attribute__((ext_vector_type(4)));

__device__ __forceinline__ ushort f2bf(float f) {
    uint u = __float_as_uint(f);
    u += 0x7FFFu + ((u >> 16) & 1u);     // round-to-nearest-even
    return (ushort)(u >> 16);
}
__device__ __forceinline__ float bf2f(ushort h) {
    return __uint_as_float(((uint)h) << 16);
}

// ---------------------------------------------------------------------------
// Prep: split each weight matrix into bf16 hi/lo, TRANSPOSED -> BT[mat][n][k].
// mat 0 = w_in, mat 1 = packed (w_off | w_mask | 0), mat 2 = w_out.
// Also packs the offset/mask bias into bpack[128].
// ---------------------------------------------------------------------------
__global__ __launch_bounds__(256) void prep_weights(
    const float* __restrict__ w_in, const float* __restrict__ w_out,
    const float* __restrict__ w_off, const float* __restrict__ b_off,
    const float* __restrict__ w_mask, const float* __restrict__ b_mask,
    ushort* __restrict__ BT, float* __restrict__ bpack)
{
    int idx = blockIdx.x * 256 + threadIdx.x;
    if (idx < 3 * 128 * 32) {
        int m  = idx >> 12;
        int r  = idx & 4095;
        int n  = r >> 5;
        int k4 = (r & 31) << 2;
        ushort h[4], l[4];
#pragma unroll
        for (int j = 0; j < 4; j++) {
            int k = k4 + j;
            float a;
            if (m == 0)      a = w_in[k * 128 + n];
            else if (m == 2) a = w_out[k * 128 + n];
            else             a = (n < 72) ? w_off[k * 72 + n]
                               : (n < 108 ? w_mask[k * 36 + (n - 72)] : 0.f);
            ushort hh = f2bf(a);
            h[j] = hh;
            l[j] = f2bf(a - bf2f(hh));
        }
        ushort* dh = BT + m * 32768 + n * 128 + k4;   // hi plane
        ushort* dl = dh + 16384;                      // lo plane
        *(ushort4*)dh = make_ushort4(h[0], h[1], h[2], h[3]);
        *(ushort4*)dl = make_ushort4(l[0], l[1], l[2], l[3]);
    } else if (idx < 3 * 128 * 32 + 128) {
        int n = idx - 3 * 128 * 32;
        bpack[n] = (n < 72) ? b_off[n] : (n < 108 ? b_mask[n - 72] : 0.f);
    }
}

// ---------------------------------------------------------------------------
// MFMA GEMM: C[M x 128] = A[M x 128] * B[128 x 128] + bias, via bf16x3 split.
// BTh/BTl: bf16 B^T [n][k]. Block = 64 rows, 4 waves x 16 rows. Grid = M/64.
// B staged once in XOR-swizzled LDS; A fragments read straight from global
// (wave's 16 rows = 8KB, L1-resident across the 4 k-steps). One barrier.
// ---------------------------------------------------------------------------
__global__ __launch_bounds__(256) void gemm_mfma(
    const float* __restrict__ A, const ushort* __restrict__ BTh,
    const ushort* __restrict__ BTl, const float* __restrict__ bias,
    float* __restrict__ C)
{
    __shared__ ushort sB[2][128][128];   // [hi/lo][n][k], byte ^= (n&7)<<4

    const int t = threadIdx.x;

    // stage B hi+lo (64KB): 16 x 16B chunks per thread, swizzled ds_write_b128
#pragma unroll
    for (int i = 0; i < 16; i++) {
        int c    = i * 256 + t;            // 0..4095
        int part = c >> 11;                // 0=hi 1=lo
        int rem  = c & 2047;
        int n    = rem >> 4;
        int kc   = (rem & 15) << 3;        // k chunk start (8 elems)
        const ushort* src = (part ? BTl : BTh) + n * 128 + kc;
        int4 v = *(const int4*)src;
        int byte = part * 32768 + n * 256 + ((kc * 2) ^ ((n & 7) << 4));
        *(int4*)((char*)sB + byte) = v;
    }
    __syncthreads();

    const int w  = t >> 6;                 // wave 0..3
    const int l  = t & 63;                 // lane
    const int lr = l & 15;                 // frag row/col index
    const int lk = l >> 4;                 // frag k-group
    const int row0 = (blockIdx.x << 6) + (w << 4);
    const float* Arow = A + (size_t)(row0 + lr) * 128;

    f32x4 acc[8];
#pragma unroll
    for (int nt = 0; nt < 8; nt++) acc[nt] = (f32x4){0.f, 0.f, 0.f, 0.f};

#pragma unroll
    for (int ks = 0; ks < 4; ks++) {
        // A fragment: 8 consecutive k, split into hi/lo bf16
        const float4 a0 = *(const float4*)(Arow + ks * 32 + lk * 8);
        const float4 a1 = *(const float4*)(Arow + ks * 32 + lk * 8 + 4);
        float av[8] = {a0.x, a0.y, a0.z, a0.w, a1.x, a1.y, a1.z, a1.w};
        bf16x8 ah, al;
#pragma unroll
        for (int j = 0; j < 8; j++) {
            ushort hh = f2bf(av[j]);
            ah[j] = (short)hh;
            al[j] = (short)f2bf(av[j] - bf2f(hh));
        }
        // B fragments for 8 n-tiles (swizzled reads)
        bf16x8 bh[8], bl[8];
#pragma unroll
        for (int nt = 0; nt < 8; nt++) {
            int n = nt * 16 + lr;
            int byte = n * 256 + (((ks * 32 + lk * 8) * 2) ^ ((n & 7) << 4));
            bh[nt] = *(const bf16x8*)((const char*)sB + byte);
            bl[nt] = *(const bf16x8*)((const char*)sB + 32768 + byte);
        }
        // 3-term split accumulate; same-acc deps spaced 8 mfmas apart
#pragma unroll
        for (int nt = 0; nt < 8; nt++)
            acc[nt] = __builtin_amdgcn_mfma_f32_16x16x32_bf16(ah, bh[nt], acc[nt], 0, 0, 0);
#pragma unroll
        for (int nt = 0; nt < 8; nt++)
            acc[nt] = __builtin_amdgcn_mfma_f32_16x16x32_bf16(al, bh[nt], acc[nt], 0, 0, 0);
#pragma unroll
        for (int nt = 0; nt < 8; nt++)
            acc[nt] = __builtin_amdgcn_mfma_f32_16x16x32_bf16(ah, bl[nt], acc[nt], 0, 0, 0);
    }

    // epilogue: C row = row0 + lk*4 + i, col = nt*16 + lr  (m89 C/D mapping)
#pragma unroll
    for (int nt = 0; nt < 8; nt++) {
        int col = nt * 16 + lr;
        float bv = bias[col];
#pragma unroll
        for (int i = 0; i < 4; i++)
            C[(size_t)(row0 + lk * 4 + i) * 128 + col] = acc[nt][i] + bv;
    }
}

// ---------------------------------------------------------------------------
// Depthwise 3x3 conv + bias + LayerNorm(C, eps=1e-6) + exact GELU
// ---------------------------------------------------------------------------
__global__ __launch_bounds__(256) void dw_ln_gelu(
    const float* __restrict__ x, const float* __restrict__ kern,
    const float* __restrict__ kbias, const float* __restrict__ gamma,
    const float* __restrict__ beta, float* __restrict__ y)
{
    const int t  = threadIdx.x;
    const int pl = t >> 5;
    const int cq = (t & 31) << 2;
    const int pix = blockIdx.x * 8 + pl;
    const int w = pix & 63;
    const int h = (pix >> 6) & 63;
    const int b = pix >> 12;

    float4 acc = make_float4(0.f, 0.f, 0.f, 0.f);
#pragma unroll
    for (int kh = 0; kh < 3; kh++) {
        int hy = h + kh - 1;
        if (hy < 0 || hy > 63) continue;
#pragma unroll
        for (int kw = 0; kw < 3; kw++) {
            int wx = w + kw - 1;
            if (wx < 0 || wx > 63) continue;
            const float4 v  = *(const float4*)(x + (((size_t)((b * 64 + hy) * 64 + wx)) << 7) + cq);
            const float4 kv = *(const float4*)(kern + ((kh * 3 + kw) << 7) + cq);
            acc.x = fmaf(v.x, kv.x, acc.x);
            acc.y = fmaf(v.y, kv.y, acc.y);
            acc.z = fmaf(v.z, kv.z, acc.z);
            acc.w = fmaf(v.w, kv.w, acc.w);
        }
    }
    const float4 kb = *(const float4*)(kbias + cq);
    acc.x += kb.x; acc.y += kb.y; acc.z += kb.z; acc.w += kb.w;

    float s  = acc.x + acc.y + acc.z + acc.w;
    float s2 = acc.x * acc.x + acc.y * acc.y + acc.z * acc.z + acc.w * acc.w;
#pragma unroll
    for (int m = 16; m >= 1; m >>= 1) {
        s  += __shfl_xor(s, m);
        s2 += __shfl_xor(s2, m);
    }
    const float mu   = s * (1.f / 128.f);
    const float var  = s2 * (1.f / 128.f) - mu * mu;
    const float rstd = 1.f / sqrtf(var + 1e-6f);

    const float4 g  = *(const float4*)(gamma + cq);
    const float4 bb = *(const float4*)(beta + cq);
    float vv[4] = {acc.x, acc.y, acc.z, acc.w};
    float gg[4] = {g.x, g.y, g.z, g.w};
    float be[4] = {bb.x, bb.y, bb.z, bb.w};
    float4 outv;
    float* po = &outv.x;
#pragma unroll
    for (int i = 0; i < 4; i++) {
        float xh = (vv[i] - mu) * rstd * gg[i] + be[i];
        po[i] = 0.5f * xh * (1.f + erff(xh * 0.70710678118654752f));
    }
    *(float4*)(y + ((size_t)pix << 7) + cq) = outv;
}

// ---------------------------------------------------------------------------
// DCNv3 sampling core. offmask row (stride 128): [0..71]=offsets, [72..107]=mask.
// ---------------------------------------------------------------------------
__global__ __launch_bounds__(256) void dcn_sample(
    const float* __restrict__ xp, const float* __restrict__ om,
    float* __restrict__ out)
{
    const int t = threadIdx.x;
    const int q = t & 3;
    const int g = (t >> 2) & 3;
    const int pix = blockIdx.x * 16 + (t >> 4);
    const int w = pix & 63;
    const int h = (pix >> 6) & 63;
    const int b = pix >> 12;

    const float* ompix = om + ((size_t)pix << 7);

    float lg[9];
    float mx = -1e30f;
#pragma unroll
    for (int p = 0; p < 9; p++) {
        lg[p] = ompix[72 + g * 9 + p];
        mx = fmaxf(mx, lg[p]);
    }
    float sum = 0.f;
#pragma unroll
    for (int p = 0; p < 9; p++) { lg[p] = expf(lg[p] - mx); sum += lg[p]; }
    const float inv = 1.f / sum;

    float4 acc0 = make_float4(0.f, 0.f, 0.f, 0.f);
    float4 acc1 = make_float4(0.f, 0.f, 0.f, 0.f);
    const int chbase = g * 32 + q * 8;

#pragma unroll
    for (int p = 0; p < 9; p++) {
        const float ox = ompix[g * 18 + 2 * p];
        const float oy = ompix[g * 18 + 2 * p + 1];
        const float px = (float)(w + p / 3 - 1) + ox;
        const float py = (float)(h + p % 3 - 1) + oy;
        const float fx0 = floorf(px), fy0 = floorf(py);
        const int x0 = (int)fx0, y0 = (int)fy0;
        const float wx1 = px - fx0, wy1 = py - fy0;
        const float wx0 = 1.f - wx1, wy0 = 1.f - wy1;
        const float m = lg[p] * inv;
        const float cw[4] = {wy0 * wx0 * m, wy0 * wx1 * m, wy1 * wx0 * m, wy1 * wx1 * m};
        const int cx[4] = {x0, x0 + 1, x0, x0 + 1};
        const int cy[4] = {y0, y0, y0 + 1, y0 + 1};
#pragma unroll
        for (int c = 0; c < 4; c++) {
            const int xx = cx[c], yy = cy[c];
            if (xx >= 0 && xx < 64 && yy >= 0 && yy < 64) {
                const float* src = xp + (((size_t)((b * 64 + yy) * 64 + xx)) << 7) + chbase;
                const float4 v0 = *(const float4*)(src);
                const float4 v1 = *(const float4*)(src + 4);
                const float wt = cw[c];
                acc0.x = fmaf(v0.x, wt, acc0.x); acc0.y = fmaf(v0.y, wt, acc0.y);
                acc0.z = fmaf(v0.z, wt, acc0.z); acc0.w = fmaf(v0.w, wt, acc0.w);
                acc1.x = fmaf(v1.x, wt, acc1.x); acc1.y = fmaf(v1.y, wt, acc1.y);
                acc1.z = fmaf(v1.z, wt, acc1.z); acc1.w = fmaf(v1.w, wt, acc1.w);
            }
        }
    }
    float* dst = out + ((size_t)pix << 7) + chbase;
    *(float4*)(dst)     = acc0;
    *(float4*)(dst + 4) = acc1;
}

// ---------------------------------------------------------------------------
extern "C" void kernel_launch(void* const* d_in, const int* in_sizes, int n_in,
                              void* d_out, int out_size, void* d_ws, size_t ws_size,
                              hipStream_t stream)
{
    const float* input   = (const float*)d_in[0];
    const float* w_in    = (const float*)d_in[1];
    const float* b_in    = (const float*)d_in[2];
    const float* w_out   = (const float*)d_in[3];
    const float* b_out   = (const float*)d_in[4];
    const float* w_off   = (const float*)d_in[5];
    const float* b_off   = (const float*)d_in[6];
    const float* w_mask  = (const float*)d_in[7];
    const float* b_mask  = (const float*)d_in[8];
    const float* dw_kern = (const float*)d_in[9];
    const float* dw_bias = (const float*)d_in[10];
    const float* ln_g    = (const float*)d_in[11];
    const float* ln_b    = (const float*)d_in[12];
    float* out = (float*)d_out;

    float* ws      = (float*)d_ws;
    float* x_proj  = ws;                       // M*128
    float* x1      = ws + PIXC;                // M*128
    float* offmask = ws + 2 * PIXC;            // M*128 (72 off | 36 mask | 20 pad)
    ushort* BT     = (ushort*)(ws + 3 * PIXC); // 3 mats x (hi|lo) x 128 x 128 bf16
    float* bpack   = (float*)(BT + 3 * 32768); // 128
    float* sampled = x1;                       // x1 dead after offmask GEMM

    prep_weights<<<49, 256, 0, stream>>>(w_in, w_out, w_off, b_off, w_mask, b_mask,
                                         BT, bpack);
    gemm_mfma<<<MPIX / 64, 256, 0, stream>>>(input, BT, BT + 16384, b_in, x_proj);
    dw_ln_gelu<<<MPIX / 8, 256, 0, stream>>>(input, dw_kern, dw_bias, ln_g, ln_b, x1);
    gemm_mfma<<<MPIX / 64, 256, 0, stream>>>(x1, BT + 32768, BT + 49152, bpack, offmask);
    dcn_sample<<<MPIX / 16, 256, 0, stream>>>(x_proj, offmask, sampled);
    gemm_mfma<<<MPIX / 64, 256, 0, stream>>>(sampled, BT + 65536, BT + 81920, b_out, out);
}